// Round 14
// baseline (499.117 us; speedup 1.0000x reference)
//
#include <hip/hip_runtime.h>
#include <math.h>

#define T_ 16
#define B_ 128
#define C3 24
#define OUT_ 64
#define EPS_ 1e-5f

typedef __attribute__((ext_vector_type(8))) short bf16x8;
typedef __attribute__((ext_vector_type(4))) float f32x4;

union FragU { unsigned u[4]; bf16x8 f; };

__device__ __forceinline__ short f2bf(float x) {
    unsigned u = __float_as_uint(x);
    return (short)((u + 0x7fffu + ((u >> 16) & 1u)) >> 16);
}
__device__ __forceinline__ void splitf(float x, short& h, short& l) {
    unsigned u = __float_as_uint(x);
    unsigned hb = (u + 0x7fffu + ((u >> 16) & 1u)) & 0xffff0000u;
    float res = x - __uint_as_float(hb);
    unsigned v = __float_as_uint(res);
    h = (short)(hb >> 16);
    l = (short)((v + 0x7fffu + ((v >> 16) & 1u)) >> 16);
}
__device__ __forceinline__ f32x4 mfma16(bf16x8 a, bf16x8 b, f32x4 c) {
    return __builtin_amdgcn_mfma_f32_16x16x32_bf16(a, b, c, 0, 0, 0);
}
// asm VGPR-form MFMA: win in rec's NON-pipelined P9 (R4). R9 lesson: never add
// prefetch register sets at the 84-reg cap (+12 live regs => +115MB FETCH).
__device__ __forceinline__ f32x4 mfma16v(bf16x8 a, bf16x8 b, f32x4 c) {
    f32x4 d;
    asm("s_nop 1\n\tv_mfma_f32_16x16x32_bf16 %0, %1, %2, %3"
        : "=v"(d)
        : "v"(a), "v"(b), "0"(c));
    return d;
}
#define MFMA_FENCE3(a0, a1, a2) \
    asm volatile("s_nop 7\n\ts_nop 7" : "+v"(a0), "+v"(a1), "+v"(a2))

__device__ __forceinline__ float fast_tanh(float z) {
    float a = fminf(fabsf(z), 9.0f);
    float e = __expf(2.0f * a);
    float t = 1.0f - 2.0f / (e + 1.0f);
    return copysignf(t, z);
}

// ---------- prep (R11/R12 version, measured equal): per-tile LDS staging ----------
__global__ __launch_bounds__(768, 1) void prep_mega(
    const float* __restrict__ Wr, const float* __restrict__ W2, const float* __restrict__ W3,
    const float* __restrict__ rel_bias,
    short* __restrict__ WrBH, short* __restrict__ WrBL,
    short* __restrict__ W2H, short* __restrict__ W2L,
    short* __restrict__ W3H, short* __restrict__ W3L,
    float* __restrict__ y0)
{
    __shared__ __attribute__((aligned(16))) char ps[37248];
    const int bid = blockIdx.x, tid = threadIdx.x;
    if (bid < 96) {                         // WrB: d = bid, 9216 outputs (12/thread)
        float* s_wr = (float*)ps;           // [96][97] padded
        const int d = bid;
        for (int q2 = tid; q2 < 9216; q2 += 768) {
            int e2 = q2 / 96, r2 = q2 % 96;
            s_wr[e2 * 97 + r2] = Wr[(size_t)d * 9216 + q2];   // contiguous read
        }
        __syncthreads();
#pragma unroll
        for (int s = 0; s < 12; ++s) {
            int q = tid + 768 * s;
            int jj = q & 7, lane = (q >> 3) & 63, f2 = q >> 9;
            int kf = f2 % 3, rt = f2 / 3;
            int col = lane & 15, grp = lane >> 4;
            int e = kf * 32 + grp * 8 + jj;
            int r = rt * 16 + col;
            short h, l; splitf(s_wr[e * 97 + r], h, l);
            size_t oidx = (size_t)d * 9216 + q;
            WrBH[oidx] = h; WrBL[oidx] = l;
        }
    } else if (bid < 120) {                 // W2: kb = bid-96, 3072 outputs (4/thread)
        float* s_w2 = (float*)ps;           // [32][97] padded
        const int kb = bid - 96;
        for (int q2 = tid; q2 < 3072; q2 += 768) {
            int rr = q2 / 96, ff = q2 % 96;
            s_w2[rr * 97 + ff] = W2[(size_t)((rr >> 2) * 96 + 4 * kb + (rr & 3)) * 96 + ff];
        }
        __syncthreads();
#pragma unroll
        for (int s = 0; s < 4; ++s) {
            int q = tid + 768 * s;
            int jj = q & 7, lane = (q >> 3) & 63, rt = q >> 9;
            int col = lane & 15, grp = lane >> 4;
            short h, l; splitf(s_w2[(jj * 4 + grp) * 97 + rt * 16 + col], h, l);
            size_t oidx = (size_t)512 * kb + (q & 511) + (size_t)12288 * rt;
            W2H[oidx] = h; W2L[oidx] = l;
        }
    } else if (bid < 144) {                 // W3: kb = bid-120, 2048 outputs
        float* s_w3 = (float*)ps;           // [32][65] padded
        const int kb = bid - 120;
        for (int q2 = tid; q2 < 2048; q2 += 768) {
            int kl = q2 >> 6, oo = q2 & 63;
            s_w3[kl * 65 + oo] = W3[(size_t)kb * 2048 + q2];   // contiguous read
        }
        __syncthreads();
        for (int q = tid; q < 2048; q += 768) {
            int jj = q & 7, lane = (q >> 3) & 63, ot = q >> 9;
            int col = lane & 15, grp = lane >> 4;
            short h, l; splitf(s_w3[(grp * 8 + jj) * 65 + ot * 16 + col], h, l);
            size_t oidx = (size_t)512 * kb + (q & 511) + (size_t)12288 * ot;
            W3H[oidx] = h; W3L[oidx] = l;
        }
    } else {                                // y0: 64 blocks, atomic accumulate
        float* s = (float*)ps;
        const int blk = bid - 144;
        const int n = blk >> 3, sl = blk & 7;
        const int r = tid % 96, p = tid / 96;
        const float* rb = rel_bias + n * 9216 + sl * 1152;
        float acc = 0.f;
        for (int i = p * 144; i < p * 144 + 144; ++i)
            acc += rb[i] * Wr[(size_t)(sl * 1152 + i) * 96 + r];
        s[tid] = acc;
        __syncthreads();
        if (tid < 96) {
            float tot = 0.f;
            for (int q = 0; q < 8; ++q) tot += s[q * 96 + tid];
            atomicAdd(&y0[n * 96 + tid], tot);
        }
    }
}

// ================= recurrence: grid 128 x 768 — ZERO persistent register state =================
// R13: Mi[12] (the last spilled per-thread array) moved to LDS; only rQ[3]
// persists in registers. Confirmed mechanism (R6/R9): register demand <-> spill
// traffic converts ~1:1 in both directions at the hard 84-arch-reg cap.
// LDS fit (161,088 <= 163,840): s_rS(768x13) -> s_S[96][97] (-2.7KB);
// s_t2L dropped (P8 stores t2 direct-to-global, identity map, nt) (-12.3KB);
// s_vp overlays s_G0/G1 (lifetimes disjoint: vp P2->P5, G0/G1 P9->P10c) with
// B6 re-added (R8: neutral) to order P10's G-reads vs next-iter P2 vp-writes.
// Mi/S addr de*97+ef0+ii: 2-way bank max (free).
__global__ __attribute__((amdgpu_flat_work_group_size(768, 768), amdgpu_waves_per_eu(3, 3)))
void stm_rec(
    const float* __restrict__ x, const float* __restrict__ Wqkv, const float* __restrict__ bqkv,
    const float* __restrict__ ln_g, const float* __restrict__ ln_b,
    const float* __restrict__ a1p, const float* __restrict__ a2p, const float* __restrict__ a3p,
    const float* __restrict__ b2,
    const float* __restrict__ item_bias, const float* __restrict__ rel_bias,
    const short* __restrict__ W2H, const short* __restrict__ W2L,
    short* __restrict__ t2g, short* __restrict__ vgb)
{
    __shared__ __attribute__((aligned(16))) char smem[161088];
    const int tid = threadIdx.x;
    const int b = blockIdx.x;
    const int wv = tid >> 6, lane = tid & 63, col = lane & 15, grp = lane >> 4;
    const float a1 = a1p[0], a2 = a2p[0], a3 = a3p[0];

    float* s_xall    = (float*)(smem);             // 6144 B
    float* s_scr     = (float*)(smem + 6144);      // 9600  (96 x 25 padded)
    float* s_scrB    = (float*)(smem + 15744);     // 3072
    float* s_Wq      = (float*)(smem + 18816);     // 9216
    float* s_lng     = (float*)(smem + 28032);     // 9600  (96 x 25 padded)
    float* s_lnb     = (float*)(smem + 37632);     // 9600  (96 x 25 padded)
    float* s_tsum    = (float*)(smem + 47232);     // 3072
    float* s_v       = (float*)(smem + 50304);     // 3072
    float* s_G0      = (float*)(smem + 53376);     // 3072 } s_vp overlays these
    float* s_G1      = (float*)(smem + 56448);     // 3072 } (4608 <= 6144)
    float* s_xtWqAll = (float*)(smem + 59520);     // 1536
    float* s_b2Wq    = (float*)(smem + 61056);     // 96
    float* s_bq      = (float*)(smem + 61152);     // 96
    float* s_b2v     = (float*)(smem + 61248);     // 384
    float* s_red     = (float*)(smem + 61632);     // 128
    short* s_tH      = (short*)(smem + 61760);     // 12416
    short* s_tL      = (short*)(smem + 74176);     // 12416
    float* s_Mi      = (float*)(smem + 86592);     // 37248 (96 x 97)
    float* s_S       = (float*)(smem + 123840);    // 37248 (96 x 97)
    float* s_vp      = (float*)(smem + 53376);     // overlay of s_G0/G1

    const int de = tid >> 3, ef0 = (tid & 7) * 12;
    const int miBase = de * 97 + ef0;
    float rQ[3];
#pragma unroll
    for (int ii = 0; ii < 12; ++ii) {
        int idx = de * 96 + ef0 + ii;
        s_Mi[miBase + ii] = item_bias[idx];
        float ss = 0.f;
        for (int n = 0; n < 8; ++n) ss += rel_bias[n * 9216 + idx];
        s_S[miBase + ii] = ss;
    }

    for (int i = tid; i < 1536; i += 768)
        s_xall[i] = x[((size_t)(i / 96) * B_ + b) * 96 + (i % 96)];
    for (int i = tid; i < 2304; i += 768) {
        int dd = i / 24, cc = i % 24;
        s_Wq[i] = Wqkv[i];
        s_lng[dd * 25 + cc] = ln_g[i];
        s_lnb[dd * 25 + cc] = ln_b[i];
    }
    if (tid < 24) s_bq[tid] = bqkv[tid];
    if (tid < 96) s_b2v[tid] = b2[tid];
    __syncthreads();
#pragma unroll
    for (int pp = 0; pp < 3; ++pp) {
        int o = tid + 768 * pp; int i = o / C3, c = o % C3;
        float acc = 0.f;
        const float* ib = item_bias + i * 96;
        for (int k = 0; k < 96; ++k) acc += ib[k] * s_Wq[k * C3 + c];
        rQ[pp] = acc;
    }
    { int c = tid % C3, p = tid / C3; float acc = 0.f;
      for (int k = 3 * p; k < 3 * p + 3; ++k) acc += s_b2v[k] * s_Wq[k * C3 + c];
      s_scr[p * 25 + c] = acc; }
    if (tid < 384) {
        int t = tid / 24, c = tid % 24;
        float acc = 0.f;
        const float* xr = s_xall + t * 96;
        for (int k = 0; k < 96; ++k) acc += xr[k] * s_Wq[k * C3 + c];
        s_xtWqAll[tid] = acc;
    }
    __syncthreads();
    if (tid < C3) { float a = 0.f; for (int p = 0; p < 32; ++p) a += s_scr[p * 25 + tid]; s_b2Wq[tid] = a; }
    __syncthreads();

    for (int t = 0; t < T_; ++t) {
        const float* xt = s_xall + t * 96;
        const float* xtWq = s_xtWqAll + t * 24;
        // P2: Mi += xt xt^T (LDS-resident RMW); p12 = Mi*S; partials -> s_vp
        {
            float xde = xt[de];
            const float4* xp = (const float4*)&xt[ef0];
            float4 x0 = xp[0], x1 = xp[1], x2 = xp[2];
            float xv[12] = { x0.x, x0.y, x0.z, x0.w,
                             x1.x, x1.y, x1.z, x1.w,
                             x2.x, x2.y, x2.z, x2.w };
            float p12[12];
#pragma unroll
            for (int ii = 0; ii < 12; ++ii) {
                float m = s_Mi[miBase + ii] + xde * xv[ii];
                s_Mi[miBase + ii] = m;
                p12[ii] = m * s_S[miBase + ii];
            }
#pragma unroll
            for (int ii = 0; ii < 12; ++ii) {
                p12[ii] += __shfl_xor(p12[ii], 8);
                p12[ii] += __shfl_xor(p12[ii], 16);
                p12[ii] += __shfl_xor(p12[ii], 32);
            }
            if ((lane >> 3) == 0) {
#pragma unroll
                for (int ii = 0; ii < 12; ++ii)
                    s_vp[wv * 96 + (lane & 7) * 12 + ii] = p12[ii];
            }
        }
        __syncthreads();                                   // B1
        // P12' (relocated since R8): uses prev-step s_scrB / s_v.
        if (t > 0) {
#pragma unroll
            for (int pp = 0; pp < 3; ++pp) {
                int o = tid + 768 * pp; int i = o / C3, c = o % C3;
                float a = s_b2Wq[c];
#pragma unroll
                for (int j = 0; j < 8; ++j) {
                    float g = s_scrB[j * C3 + c] + s_scrB[192 + j * C3 + c]
                            + s_scrB[384 + j * C3 + c] + s_scrB[576 + j * C3 + c];
                    a += s_v[j * 96 + i] * g;
                }
                rQ[pp] += a3 * a;
            }
        }
        // P5: Vtr redundant-reduce, rQ += xt⊗xtWq, qkv + LN sums
        {
            const int i0 = tid / 24, c = tid % 24;
            float ls = 0.f, lq = 0.f;
#pragma unroll
            for (int pp = 0; pp < 3; ++pp) {
                const int i = i0 + 32 * pp;
                float vtr = 0.f;
#pragma unroll
                for (int w = 0; w < 12; ++w) vtr += s_vp[w * 96 + i];
                rQ[pp] += xt[i] * xtWq[c];
                float qv = rQ[pp] + a2 * vtr * xtWq[c] + s_bq[c];
                s_scr[i * 25 + c] = qv;
                ls += qv; lq += qv * qv;
            }
            for (int off = 32; off > 0; off >>= 1) { ls += __shfl_down(ls, off); lq += __shfl_down(lq, off); }
            if (lane == 0) { s_red[wv] = ls; s_red[16 + wv] = lq; }
        }
        __syncthreads();                                   // B3
        // P8: inline LN + v + t; t2 stored DIRECT to global (identity map, nt)
        {
            float S = 0.f, Qs = 0.f;
            for (int w = 0; w < 12; ++w) { S += s_red[w]; Qs += s_red[16 + w]; }
            const float mu = S * (1.0f / 2304.f);
            const float rstd = rsqrtf(Qs * (1.0f / 2304.f) - mu * mu + EPS_);
            const int j = tid / 96, d = tid % 96;
            const int d25 = d * 25;
            {
                int o = d25 + 16 + j;
                float vv = (s_scr[o] - mu) * rstd * s_lng[o] + s_lnb[o];
                s_v[tid] = vv;
                __builtin_nontemporal_store(f2bf(vv), &vgb[((size_t)(t * B_ + b)) * 768 + tid]);
            }
            int ok = d25 + 8 + j;
            float kk = (s_scr[ok] - mu) * rstd * s_lng[ok] + s_lnb[ok];
            const size_t tb2 = ((size_t)(t * B_ + b)) * 6144 + d * 8 + j;
            float ts = 0.f;
            const int tb = j * 776 + d * 8;
#pragma unroll
            for (int q = 0; q < 4; ++q) {
                int oq0 = d25 + 2 * q, oq1 = oq0 + 1;
                float q0 = (s_scr[oq0] - mu) * rstd * s_lng[oq0] + s_lnb[oq0];
                float q1 = (s_scr[oq1] - mu) * rstd * s_lng[oq1] + s_lnb[oq1];
                float tv0 = fast_tanh(q0 * kk);
                float tv1 = fast_tanh(q1 * kk);
                ts += tv0 + tv1;
                short h0, l0, h1, l1;
                splitf(tv0, h0, l0); splitf(tv1, h1, l1);
                *(unsigned*)&s_tH[tb + 2 * q] =
                    (unsigned)(unsigned short)h0 | ((unsigned)(unsigned short)h1 << 16);
                *(unsigned*)&s_tL[tb + 2 * q] =
                    (unsigned)(unsigned short)l0 | ((unsigned)(unsigned short)l1 << 16);
                __builtin_nontemporal_store(h0, &t2g[tb2 + (size_t)(2 * q) * 768]);
                __builtin_nontemporal_store(h1, &t2g[tb2 + (size_t)(2 * q + 1) * 768]);
            }
            s_tsum[j * 96 + d] = ts;
        }
        __syncthreads();                                   // B4
        // P9: G-GEMM (asm MFMA, 3 accumulators, no LL term)
        {
            const int rt = wv % 6, kh = wv / 6;
            f32x4 aHH = {0,0,0,0}, aLH = {0,0,0,0}, aHL = {0,0,0,0};
#pragma unroll 4
            for (int s2 = 0; s2 < 12; ++s2) {
                int kb = kh * 12 + s2;
                bf16x8 ah = {}; bf16x8 al = {};
                if (col < 8) {
                    ah = *(const bf16x8*)&s_tH[col * 776 + kb * 32 + grp * 8];
                    al = *(const bf16x8*)&s_tL[col * 776 + kb * 32 + grp * 8];
                }
                int fo = ((rt * 24 + kb) * 64 + lane) * 8;
                bf16x8 bh = *(const bf16x8*)&W2H[fo];
                bf16x8 bl = *(const bf16x8*)&W2L[fo];
                aHH = mfma16v(ah, bh, aHH);
                aLH = mfma16v(al, bh, aLH);
                aHL = mfma16v(ah, bl, aHL);
            }
            MFMA_FENCE3(aHH, aLH, aHL);
            f32x4 accG;
#pragma unroll
            for (int reg = 0; reg < 4; ++reg) accG[reg] = (aHH[reg] + aLH[reg]) + aHL[reg];
            float* dst = (kh == 0) ? s_G0 : s_G1;
            if (grp < 2) {
#pragma unroll
                for (int reg = 0; reg < 4; ++reg)
                    dst[(grp * 4 + reg) * 96 + rt * 16 + col] = accG[reg];
            }
        }
        __syncthreads();                                   // B5
        // P10a: GWq partials
        { int oo = tid % 192, q = tid / 192; int jg = oo / C3, cc = oo % C3;
          float a = 0.f;
          for (int f = q * 24; f < q * 24 + 24; ++f)
              a += (s_G0[jg * 96 + f] + s_G1[jg * 96 + f]) * s_Wq[f * C3 + cc];
          s_scrB[tid] = a; }
        // P10b: S update (LDS-resident)
        {
            float sn[12];
#pragma unroll
            for (int ii = 0; ii < 12; ++ii) sn[ii] = 0.f;
#pragma unroll
            for (int j = 0; j < 8; ++j) {
                const float tj = s_tsum[j * 96 + de];
                const float4* vp = (const float4*)&s_v[j * 96 + ef0];
#pragma unroll
                for (int q4 = 0; q4 < 3; ++q4) {
                    float4 vv = vp[q4];
                    sn[q4*4+0] += tj*vv.x; sn[q4*4+1] += tj*vv.y;
                    sn[q4*4+2] += tj*vv.z; sn[q4*4+3] += tj*vv.w;
                }
            }
#pragma unroll
            for (int ii = 0; ii < 12; ++ii)
                s_S[miBase + ii] = a1 * s_S[miBase + ii] + sn[ii];
        }
        // P10c: Mi update (LDS-resident)
        {
            float r2[12];
#pragma unroll
            for (int ii = 0; ii < 12; ++ii) r2[ii] = 0.f;
#pragma unroll
            for (int j = 0; j < 8; ++j) {
                const float vj = s_v[j * 96 + de];
                const float4* g0 = (const float4*)&s_G0[j * 96 + ef0];
                const float4* g1 = (const float4*)&s_G1[j * 96 + ef0];
#pragma unroll
                for (int q4 = 0; q4 < 3; ++q4) {
                    float4 ga = g0[q4], gb = g1[q4];
                    r2[q4*4+0] += vj*(ga.x+gb.x); r2[q4*4+1] += vj*(ga.y+gb.y);
                    r2[q4*4+2] += vj*(ga.z+gb.z); r2[q4*4+3] += vj*(ga.w+gb.w);
                }
            }
#pragma unroll
            for (int ii = 0; ii < 12; ++ii)
                s_Mi[miBase + ii] += a3 * (r2[ii] + s_b2v[ef0 + ii]);
        }
        __syncthreads();                                   // B6 (re-added: orders
        // P10's G0/G1 reads before next-iteration P2's s_vp overlay writes)
    }
}

// ================= tail: grid 258, software-pipelined d-loop (builtin MFMA) =================
__global__ __launch_bounds__(384, 2) void stm_tail(
    const short* __restrict__ WrBH, const short* __restrict__ WrBL,
    const short* __restrict__ W3H, const short* __restrict__ W3L,
    const short* __restrict__ t2g, const short* __restrict__ vgb,
    const float* __restrict__ y0, const float* __restrict__ br,
    const float* __restrict__ W3f, const float* __restrict__ b3,
    float* __restrict__ zg, float* __restrict__ c0v, float* __restrict__ cbrv)
{
    __shared__ __attribute__((aligned(16))) short sPT[6 * 5120];   // 61440 B
    short* DyH = sPT;                 // overlay after PT consumed: 8t x 776 = 12416 B
    short* DyL = sPT + 6208;          // 12416 B

    const int tid = threadIdx.x;

    if (blockIdx.x >= 256) {          // c0 / cbr blocks (one-time GEMVs)
        float* red = (float*)sPT;
        const int o = tid & 63, seg = tid >> 6;     // seg 0..5, 128 i each
        if (blockIdx.x == 256) {
            float pa = 0.f;
            for (int i = seg * 128; i < seg * 128 + 128; ++i)
                pa += y0[i] * W3f[(size_t)i * 64 + o];
            red[seg * 64 + o] = pa;
            __syncthreads();
            if (tid < 64) {
                float s = 0.f;
                for (int q = 0; q < 6; ++q) s += red[q * 64 + tid];
                c0v[tid] = s;
            }
        } else {
            float pb = 0.f;
            for (int i = seg * 128; i < seg * 128 + 128; ++i)
                pb += br[i % 96] * W3f[(size_t)i * 64 + o];
            red[seg * 64 + o] = pb;
            __syncthreads();
            if (tid < 64) {
                float s = b3[tid];
                for (int q = 0; q < 6; ++q) s += red[q * 64 + tid];
                cbrv[tid] = s;
            }
        }
        return;
    }

    const int b = blockIdx.x & 127, tg = blockIdx.x >> 7;
    const int wv6 = tid >> 6, lane = tid & 63, col = lane & 15, grp = lane >> 4;
    const int rt6 = wv6;
    const int th = tg * 8;
    short* PTw = sPT + wv6 * 5120;

    bf16x8 Av[4][3];
#pragma unroll
    for (int p = 0; p < 4; ++p)
#pragma unroll
        for (int kf = 0; kf < 3; ++kf) {
            int t = th + 2 * p + (col >> 3);
            int j = col & 7;
            uint4 z = *(const uint4*)&vgb[((size_t)(t * B_ + b)) * 768 + j * 96 + kf * 32 + grp * 8];
            FragU F; F.u[0] = z.x; F.u[1] = z.y; F.u[2] = z.z; F.u[3] = z.w;
            Av[p][kf] = F.f;
        }
    f32x4 accD[8];
#pragma unroll
    for (int btl = 0; btl < 8; ++btl) accD[btl] = (f32x4){0.f, 0.f, 0.f, 0.f};

    FragU A2r[8];
    bf16x8 bhA[3], blA[3], bhB[3], blB[3];
#pragma unroll
    for (int kf = 0; kf < 3; ++kf) {
        const int fo = ((0 * 18 + rt6 * 3 + kf) * 64 + lane) * 8;
        bhA[kf] = *(const bf16x8*)&WrBH[fo];
        blA[kf] = *(const bf16x8*)&WrBL[fo];
    }

#define TAIL_BODY(DL, CH, CL, NH, NL)                                          \
    {                                                                          \
        const int d = g4 * 4 + (DL);                                           \
        if ((DL) < 3 || g4 < 23) {                                             \
            const int dn = d + 1;                                              \
            _Pragma("unroll")                                                  \
            for (int kf = 0; kf < 3; ++kf) {                                   \
                const int fo = ((dn * 18 + rt6 * 3 + kf) * 64 + lane) * 8;     \
                NH[kf] = *(const bf16x8*)&WrBH[fo];                            \
                NL[kf] = *(const bf16x8*)&WrBL[fo];                            \
            }                                                                  \
        }                                                                      \
        if ((DL) == 1) {                                                       \
            _Pragma("unroll")                                                  \
            for (int btl = 0; btl < 8; ++btl) {                                \
                A2r[btl].u[0] = 0; A2r[btl].u[1] = 0;                          \
                A2r[btl].u[2] = 0; A2r[btl].u[3] = 0;                          \
                if (col < 8) {                                                 \
                    const int tt = th + btl;                                   \
                    uint4 z = *(const uint4*)&t2g[((size_t)(tt * B_ + b)) * 6144 \
                              + col * 768 + g4 * 32 + grp * 8];                \
                    A2r[btl].u[0] = z.x; A2r[btl].u[1] = z.y;                  \
                    A2r[btl].u[2] = z.z; A2r[btl].u[3] = z.w;                  \
                }                                                              \
            }                                                                  \
        }                                                                      \
        f32x4 aPv[4];                                                          \
        _Pragma("unroll")                                                      \
        for (int p = 0; p < 4; ++p) aPv[p] = (f32x4){0.f, 0.f, 0.f, 0.f};      \
        _Pragma("unroll")                                                      \
        for (int kf = 0; kf < 3; ++kf) {                                       \
            _Pragma("unroll")                                                  \
            for (int p = 0; p < 4; ++p) aPv[p] = mfma16(Av[p][kf], CH[kf], aPv[p]); \
            _Pragma("unroll")                                                  \
            for (int p = 0; p < 4; ++p) aPv[p] = mfma16(Av[p][kf], CL[kf], aPv[p]); \
        }                                                                      \
        {                                                                      \
            const int j0 = (grp & 1) * 4;                                      \
            const int bo = grp >> 1;                                           \
            _Pragma("unroll")                                                  \
            for (int p = 0; p < 4; ++p) {                                      \
                const int btl = 2 * p + bo;                                    \
                uint2 uu;                                                      \
                uu.x = (unsigned)(unsigned short)f2bf(aPv[p][0]) |             \
                       ((unsigned)(unsigned short)f2bf(aPv[p][1]) << 16);      \
                uu.y = (unsigned)(unsigned short)f2bf(aPv[p][2]) |             \
                       ((unsigned)(unsigned short)f2bf(aPv[p][3]) << 16);      \
                *(uint2*)&PTw[btl * 640 + col * 40 + (DL) * 8 + j0] = uu;      \
            }                                                                  \
        }                                                                      \
        if ((DL) == 3) {                                                       \
            _Pragma("unroll")                                                  \
            for (int btl = 0; btl < 8; ++btl) {                                \
                bf16x8 B2 = *(const bf16x8*)&PTw[btl * 640 + col * 40 + grp * 8]; \
                accD[btl] = mfma16(A2r[btl].f, B2, accD[btl]);                 \
            }                                                                  \
        }                                                                      \
    }

    for (int g4 = 0; g4 < 24; ++g4) {
        TAIL_BODY(0, bhA, blA, bhB, blB)
        TAIL_BODY(1, bhB, blB, bhA, blA)
        TAIL_BODY(2, bhA, blA, bhB, blB)
        TAIL_BODY(3, bhB, blB, bhA, blA)
    }
#undef TAIL_BODY

    __syncthreads();
    // Dy split planes for this block's 8 t (local rows 0..7)
    if (grp < 2) {
#pragma unroll
        for (int btl = 0; btl < 8; ++btl)
#pragma unroll
            for (int reg = 0; reg < 4; ++reg) {
                short h, l; splitf(accD[btl][reg], h, l);
                int idx = btl * 776 + (grp * 4 + reg) * 96 + rt6 * 16 + col;
                DyH[idx] = h; DyL[idx] = l;
            }
    }
    __syncthreads();
    // Z-GEMM: waves 0..3 = o-tiles, A rows = local t (8 valid), k = 768
    if (wv6 < 4) {
        const int ot = wv6;
        f32x4 zHH = {0,0,0,0}, zLH = {0,0,0,0}, zHL = {0,0,0,0};
#pragma unroll 4
        for (int kb = 0; kb < 24; ++kb) {
            bf16x8 ah = {}; bf16x8 al = {};
            if (col < 8) {
                ah = *(const bf16x8*)&DyH[col * 776 + kb * 32 + grp * 8];
                al = *(const bf16x8*)&DyL[col * 776 + kb * 32 + grp * 8];
            }
            int fo = ((ot * 24 + kb) * 64 + lane) * 8;
            bf16x8 bhw = *(const bf16x8*)&W3H[fo];
            bf16x8 blw = *(const bf16x8*)&W3L[fo];
            zHH = mfma16(ah, bhw, zHH);
            zLH = mfma16(al, bhw, zLH);
            zHL = mfma16(ah, blw, zHL);
        }
        if (grp < 2) {
#pragma unroll
            for (int reg = 0; reg < 4; ++reg) {
                int tl = grp * 4 + reg;
                zg[((size_t)(b * 16 + th + tl)) * 64 + ot * 16 + col] = zHH[reg] + zLH[reg] + zHL[reg];
            }
        }
    }
}

// ================= fin: pure scan over t, grid 128 x 64 =================
__global__ __launch_bounds__(64) void stm_fin(
    const float* __restrict__ a1p, const float* __restrict__ zg,
    const float* __restrict__ c0v, const float* __restrict__ cbrv,
    float* __restrict__ out)
{
    const int tid = threadIdx.x, b = blockIdx.x;
    const float a1 = a1p[0];
    float u = c0v[tid];
    const float cbr = cbrv[tid];
    for (int t = 0; t < T_; ++t) {
        u = a1 * u + zg[((size_t)(b * 16 + t)) * 64 + tid];
        out[((size_t)(t * B_ + b)) * OUT_ + tid] = u + cbr;
    }
}

extern "C" void kernel_launch(void* const* d_in, const int* in_sizes, int n_in,
                              void* d_out, int out_size, void* d_ws, size_t ws_size,
                              hipStream_t stream) {
    const float* x         = (const float*)d_in[0];
    const float* Wqkv      = (const float*)d_in[1];
    const float* bqkv      = (const float*)d_in[2];
    const float* ln_g      = (const float*)d_in[3];
    const float* ln_b      = (const float*)d_in[4];
    const float* a1        = (const float*)d_in[5];
    const float* a2        = (const float*)d_in[6];
    const float* a3        = (const float*)d_in[7];
    const float* W2        = (const float*)d_in[8];
    const float* b2        = (const float*)d_in[9];
    const float* Wr        = (const float*)d_in[10];
    const float* br        = (const float*)d_in[11];
    const float* W3        = (const float*)d_in[12];
    const float* b3        = (const float*)d_in[13];
    const float* item_bias = (const float*)d_in[14];
    const float* rel_bias  = (const float*)d_in[15];
    float* out = (float*)d_out;

    char* ws = (char*)d_ws;
    short* WrBH = (short*)ws;                          // 1,769,472 B
    short* WrBL = (short*)(ws + 1769472);              // 1,769,472 B
    short* W2H  = (short*)(ws + 3538944);              //   147,456 B
    short* W2L  = (short*)(ws + 3686400);              //   147,456 B
    short* W3H  = (short*)(ws + 3833856);              //    98,304 B
    short* W3L  = (short*)(ws + 3932160);              //    98,304 B
    float* y0   = (float*)(ws + 4030464);              //     3,072 B
    short* t2g  = (short*)(ws + 4034048);              // 25,165,824 B
    short* vgb  = (short*)(ws + 29199872);             //  3,145,728 B
    float* zg   = (float*)(ws + 32345600);             //    524,288 B
    float* c0v  = (float*)(ws + 32869888);             //       256 B
    float* cbrv = (float*)(ws + 32870144);             //       256 B

    hipMemsetAsync(y0, 0, 3072, stream);
    hipLaunchKernelGGL(prep_mega, dim3(208), dim3(768), 0, stream,
                       Wr, W2, W3, rel_bias, WrBH, WrBL, W2H, W2L, W3H, W3L, y0);
    hipLaunchKernelGGL(stm_rec, dim3(B_), dim3(768), 0, stream,
                       x, Wqkv, bqkv, ln_g, ln_b, a1, a2, a3,
                       b2, item_bias, rel_bias, W2H, W2L, t2g, vgb);
    hipLaunchKernelGGL(stm_tail, dim3(258), dim3(384), 0, stream,
                       WrBH, WrBL, W3H, W3L, t2g, vgb,
                       y0, br, W3, b3, zg, c0v, cbrv);
    hipLaunchKernelGGL(stm_fin, dim3(B_), dim3(64), 0, stream,
                       a1, zg, c0v, cbrv, out);
}

// Round 15
// 459.491 us; speedup vs baseline: 1.0862x; 1.0862x over previous
//
#include <hip/hip_runtime.h>
#include <math.h>

#define T_ 16
#define B_ 128
#define C3 24
#define OUT_ 64
#define EPS_ 1e-5f

typedef __attribute__((ext_vector_type(8))) short bf16x8;
typedef __attribute__((ext_vector_type(4))) float f32x4;
typedef __attribute__((ext_vector_type(4))) unsigned uint32x4;

union FragU { unsigned u[4]; bf16x8 f; };

__device__ __forceinline__ short f2bf(float x) {
    unsigned u = __float_as_uint(x);
    return (short)((u + 0x7fffu + ((u >> 16) & 1u)) >> 16);
}
__device__ __forceinline__ void splitf(float x, short& h, short& l) {
    unsigned u = __float_as_uint(x);
    unsigned hb = (u + 0x7fffu + ((u >> 16) & 1u)) & 0xffff0000u;
    float res = x - __uint_as_float(hb);
    unsigned v = __float_as_uint(res);
    h = (short)(hb >> 16);
    l = (short)((v + 0x7fffu + ((v >> 16) & 1u)) >> 16);
}
__device__ __forceinline__ f32x4 mfma16(bf16x8 a, bf16x8 b, f32x4 c) {
    return __builtin_amdgcn_mfma_f32_16x16x32_bf16(a, b, c, 0, 0, 0);
}
// asm VGPR-form MFMA: win in rec's NON-pipelined P9 (R4). R9/R13 lessons:
// never add live registers at the 84-reg cap; never break the coalesced
// s_t2L -> uint4 t2g dump (scalar scatter = ~8x write amplification).
__device__ __forceinline__ f32x4 mfma16v(bf16x8 a, bf16x8 b, f32x4 c) {
    f32x4 d;
    asm("s_nop 1\n\tv_mfma_f32_16x16x32_bf16 %0, %1, %2, %3"
        : "=v"(d)
        : "v"(a), "v"(b), "0"(c));
    return d;
}
#define MFMA_FENCE3(a0, a1, a2) \
    asm volatile("s_nop 7\n\ts_nop 7" : "+v"(a0), "+v"(a1), "+v"(a2))

__device__ __forceinline__ float fast_tanh(float z) {
    float a = fminf(fabsf(z), 9.0f);
    float e = __expf(2.0f * a);
    float t = 1.0f - 2.0f / (e + 1.0f);
    return copysignf(t, z);
}

// ---------- prep (R11/R12 version, measured equal to original): per-tile LDS staging ----------
__global__ __launch_bounds__(768, 1) void prep_mega(
    const float* __restrict__ Wr, const float* __restrict__ W2, const float* __restrict__ W3,
    const float* __restrict__ rel_bias,
    short* __restrict__ WrBH, short* __restrict__ WrBL,
    short* __restrict__ W2H, short* __restrict__ W2L,
    short* __restrict__ W3H, short* __restrict__ W3L,
    float* __restrict__ y0)
{
    __shared__ __attribute__((aligned(16))) char ps[37248];
    const int bid = blockIdx.x, tid = threadIdx.x;
    if (bid < 96) {                         // WrB: d = bid, 9216 outputs (12/thread)
        float* s_wr = (float*)ps;           // [96][97] padded
        const int d = bid;
        for (int q2 = tid; q2 < 9216; q2 += 768) {
            int e2 = q2 / 96, r2 = q2 % 96;
            s_wr[e2 * 97 + r2] = Wr[(size_t)d * 9216 + q2];   // contiguous read
        }
        __syncthreads();
#pragma unroll
        for (int s = 0; s < 12; ++s) {
            int q = tid + 768 * s;
            int jj = q & 7, lane = (q >> 3) & 63, f2 = q >> 9;
            int kf = f2 % 3, rt = f2 / 3;
            int col = lane & 15, grp = lane >> 4;
            int e = kf * 32 + grp * 8 + jj;
            int r = rt * 16 + col;
            short h, l; splitf(s_wr[e * 97 + r], h, l);
            size_t oidx = (size_t)d * 9216 + q;
            WrBH[oidx] = h; WrBL[oidx] = l;
        }
    } else if (bid < 120) {                 // W2: kb = bid-96, 3072 outputs (4/thread)
        float* s_w2 = (float*)ps;           // [32][97] padded
        const int kb = bid - 96;
        for (int q2 = tid; q2 < 3072; q2 += 768) {
            int rr = q2 / 96, ff = q2 % 96;
            s_w2[rr * 97 + ff] = W2[(size_t)((rr >> 2) * 96 + 4 * kb + (rr & 3)) * 96 + ff];
        }
        __syncthreads();
#pragma unroll
        for (int s = 0; s < 4; ++s) {
            int q = tid + 768 * s;
            int jj = q & 7, lane = (q >> 3) & 63, rt = q >> 9;
            int col = lane & 15, grp = lane >> 4;
            short h, l; splitf(s_w2[(jj * 4 + grp) * 97 + rt * 16 + col], h, l);
            size_t oidx = (size_t)512 * kb + (q & 511) + (size_t)12288 * rt;
            W2H[oidx] = h; W2L[oidx] = l;
        }
    } else if (bid < 144) {                 // W3: kb = bid-120, 2048 outputs
        float* s_w3 = (float*)ps;           // [32][65] padded
        const int kb = bid - 120;
        for (int q2 = tid; q2 < 2048; q2 += 768) {
            int kl = q2 >> 6, oo = q2 & 63;
            s_w3[kl * 65 + oo] = W3[(size_t)kb * 2048 + q2];   // contiguous read
        }
        __syncthreads();
        for (int q = tid; q < 2048; q += 768) {
            int jj = q & 7, lane = (q >> 3) & 63, ot = q >> 9;
            int col = lane & 15, grp = lane >> 4;
            short h, l; splitf(s_w3[(grp * 8 + jj) * 65 + ot * 16 + col], h, l);
            size_t oidx = (size_t)512 * kb + (q & 511) + (size_t)12288 * ot;
            W3H[oidx] = h; W3L[oidx] = l;
        }
    } else {                                // y0: 64 blocks, atomic accumulate
        float* s = (float*)ps;
        const int blk = bid - 144;
        const int n = blk >> 3, sl = blk & 7;
        const int r = tid % 96, p = tid / 96;
        const float* rb = rel_bias + n * 9216 + sl * 1152;
        float acc = 0.f;
        for (int i = p * 144; i < p * 144 + 144; ++i)
            acc += rb[i] * Wr[(size_t)(sl * 1152 + i) * 96 + r];
        s[tid] = acc;
        __syncthreads();
        if (tid < 96) {
            float tot = 0.f;
            for (int q = 0; q < 8; ++q) tot += s[q * 96 + tid];
            atomicAdd(&y0[n * 96 + tid], tot);
        }
    }
}

// ================= recurrence: grid 128 x 768 (R10/R12 best config, 290us measured) =================
__global__ __attribute__((amdgpu_flat_work_group_size(768, 768), amdgpu_waves_per_eu(3, 3)))
void stm_rec(
    const float* __restrict__ x, const float* __restrict__ Wqkv, const float* __restrict__ bqkv,
    const float* __restrict__ ln_g, const float* __restrict__ ln_b,
    const float* __restrict__ a1p, const float* __restrict__ a2p, const float* __restrict__ a3p,
    const float* __restrict__ b2,
    const float* __restrict__ item_bias, const float* __restrict__ rel_bias,
    const short* __restrict__ W2H, const short* __restrict__ W2L,
    short* __restrict__ t2g, short* __restrict__ vgb)
{
    __shared__ __attribute__((aligned(16))) char smem[143424];
    const int tid = threadIdx.x;
    const int b = blockIdx.x;
    const int wv = tid >> 6, lane = tid & 63, col = lane & 15, grp = lane >> 4;
    const float a1 = a1p[0], a2 = a2p[0], a3 = a3p[0];

    float* s_xall    = (float*)(smem);             // 6144 B
    float* s_scr     = (float*)(smem + 6144);      // 9600  (96 x 25 padded)
    float* s_scrB    = (float*)(smem + 15744);     // 3072
    float* s_Wq      = (float*)(smem + 18816);     // 9216
    float* s_lng     = (float*)(smem + 28032);     // 9600  (96 x 25 padded)
    float* s_lnb     = (float*)(smem + 37632);     // 9600  (96 x 25 padded)
    float* s_tsum    = (float*)(smem + 47232);     // 3072
    float* s_v       = (float*)(smem + 50304);     // 3072
    float* s_G0      = (float*)(smem + 53376);     // 3072
    float* s_G1      = (float*)(smem + 56448);     // 3072
    float* s_xtWqAll = (float*)(smem + 59520);     // 1536
    float* s_b2Wq    = (float*)(smem + 61056);     // 96
    float* s_bq      = (float*)(smem + 61152);     // 96
    float* s_b2v     = (float*)(smem + 61248);     // 384
    float* s_red     = (float*)(smem + 61632);     // 128
    short* s_tH      = (short*)(smem + 61760);     // 12416
    short* s_tL      = (short*)(smem + 74176);     // 12416
    short* s_t2L     = (short*)(smem + 86592);     // 12288
    float* s_vp      = (float*)(smem + 98880);     // 4608 (Vtr partials)
    float* s_rS      = (float*)(smem + 103488);    // 39936 (768 x 13 padded)

    const int de = tid >> 3, ef0 = (tid & 7) * 12;
    const int t13 = tid * 13;
    float rMi[12], rQ[3];
#pragma unroll
    for (int ii = 0; ii < 12; ++ii) {
        int idx = de * 96 + ef0 + ii;
        rMi[ii] = item_bias[idx];
        float ss = 0.f;
        for (int n = 0; n < 8; ++n) ss += rel_bias[n * 9216 + idx];
        s_rS[t13 + ii] = ss;
    }

    for (int i = tid; i < 1536; i += 768)
        s_xall[i] = x[((size_t)(i / 96) * B_ + b) * 96 + (i % 96)];
    for (int i = tid; i < 2304; i += 768) {
        int dd = i / 24, cc = i % 24;
        s_Wq[i] = Wqkv[i];
        s_lng[dd * 25 + cc] = ln_g[i];
        s_lnb[dd * 25 + cc] = ln_b[i];
    }
    if (tid < 24) s_bq[tid] = bqkv[tid];
    if (tid < 96) s_b2v[tid] = b2[tid];
    __syncthreads();
#pragma unroll
    for (int pp = 0; pp < 3; ++pp) {
        int o = tid + 768 * pp; int i = o / C3, c = o % C3;
        float acc = 0.f;
        const float* ib = item_bias + i * 96;
        for (int k = 0; k < 96; ++k) acc += ib[k] * s_Wq[k * C3 + c];
        rQ[pp] = acc;
    }
    { int c = tid % C3, p = tid / C3; float acc = 0.f;
      for (int k = 3 * p; k < 3 * p + 3; ++k) acc += s_b2v[k] * s_Wq[k * C3 + c];
      s_scr[p * 25 + c] = acc; }
    if (tid < 384) {
        int t = tid / 24, c = tid % 24;
        float acc = 0.f;
        const float* xr = s_xall + t * 96;
        for (int k = 0; k < 96; ++k) acc += xr[k] * s_Wq[k * C3 + c];
        s_xtWqAll[tid] = acc;
    }
    __syncthreads();
    if (tid < C3) { float a = 0.f; for (int p = 0; p < 32; ++p) a += s_scr[p * 25 + tid]; s_b2Wq[tid] = a; }
    __syncthreads();

    for (int t = 0; t < T_; ++t) {
        const float* xt = s_xall + t * 96;
        const float* xtWq = s_xtWqAll + t * 24;
        // P2: Mi += xt xt^T ; Vtr partials -> s_vp
        {
            float xde = xt[de];
            const float4* xp = (const float4*)&xt[ef0];
            float4 x0 = xp[0], x1 = xp[1], x2 = xp[2];
            rMi[0] += xde * x0.x; rMi[1] += xde * x0.y; rMi[2] += xde * x0.z; rMi[3] += xde * x0.w;
            rMi[4] += xde * x1.x; rMi[5] += xde * x1.y; rMi[6] += xde * x1.z; rMi[7] += xde * x1.w;
            rMi[8] += xde * x2.x; rMi[9] += xde * x2.y; rMi[10] += xde * x2.z; rMi[11] += xde * x2.w;
        }
        {
            float p12[12];
#pragma unroll
            for (int ii = 0; ii < 12; ++ii) p12[ii] = rMi[ii] * s_rS[t13 + ii];
#pragma unroll
            for (int ii = 0; ii < 12; ++ii) {
                p12[ii] += __shfl_xor(p12[ii], 8);
                p12[ii] += __shfl_xor(p12[ii], 16);
                p12[ii] += __shfl_xor(p12[ii], 32);
            }
            if ((lane >> 3) == 0) {
#pragma unroll
                for (int ii = 0; ii < 12; ++ii)
                    s_vp[wv * 96 + (lane & 7) * 12 + ii] = p12[ii];
            }
        }
        __syncthreads();                                   // B1
        // P12' (relocated; B6 deleted in R8): uses prev-step s_scrB / s_v.
        if (t > 0) {
#pragma unroll
            for (int pp = 0; pp < 3; ++pp) {
                int o = tid + 768 * pp; int i = o / C3, c = o % C3;
                float a = s_b2Wq[c];
#pragma unroll
                for (int j = 0; j < 8; ++j) {
                    float g = s_scrB[j * C3 + c] + s_scrB[192 + j * C3 + c]
                            + s_scrB[384 + j * C3 + c] + s_scrB[576 + j * C3 + c];
                    a += s_v[j * 96 + i] * g;
                }
                rQ[pp] += a3 * a;
            }
        }
        // P5: Vtr redundant-reduce, rQ += xt⊗xtWq, qkv + LN sums
        {
            const int i0 = tid / 24, c = tid % 24;
            float ls = 0.f, lq = 0.f;
#pragma unroll
            for (int pp = 0; pp < 3; ++pp) {
                const int i = i0 + 32 * pp;
                float vtr = 0.f;
#pragma unroll
                for (int w = 0; w < 12; ++w) vtr += s_vp[w * 96 + i];
                rQ[pp] += xt[i] * xtWq[c];
                float qv = rQ[pp] + a2 * vtr * xtWq[c] + s_bq[c];
                s_scr[i * 25 + c] = qv;
                ls += qv; lq += qv * qv;
            }
            for (int off = 32; off > 0; off >>= 1) { ls += __shfl_down(ls, off); lq += __shfl_down(lq, off); }
            if (lane == 0) { s_red[wv] = ls; s_red[16 + wv] = lq; }
        }
        __syncthreads();                                   // B3
        // P8: inline LN + v + t  (stride-25 padded reads: conflict-free)
        {
            float S = 0.f, Qs = 0.f;
            for (int w = 0; w < 12; ++w) { S += s_red[w]; Qs += s_red[16 + w]; }
            const float mu = S * (1.0f / 2304.f);
            const float rstd = rsqrtf(Qs * (1.0f / 2304.f) - mu * mu + EPS_);
            const int j = tid / 96, d = tid % 96;
            const int d25 = d * 25;
            {
                int o = d25 + 16 + j;
                float vv = (s_scr[o] - mu) * rstd * s_lng[o] + s_lnb[o];
                s_v[tid] = vv;
                __builtin_nontemporal_store(f2bf(vv), &vgb[((size_t)(t * B_ + b)) * 768 + tid]);
            }
            int ok = d25 + 8 + j;
            float kk = (s_scr[ok] - mu) * rstd * s_lng[ok] + s_lnb[ok];
            float tv0, tv1;
            unsigned hp0, hp1, hp2, hp3, lp0, lp1, lp2, lp3;
            float ts = 0.f;
#pragma unroll
            for (int q = 0; q < 4; ++q) {
                int oq0 = d25 + 2 * q, oq1 = oq0 + 1;
                float q0 = (s_scr[oq0] - mu) * rstd * s_lng[oq0] + s_lnb[oq0];
                float q1 = (s_scr[oq1] - mu) * rstd * s_lng[oq1] + s_lnb[oq1];
                tv0 = fast_tanh(q0 * kk);
                tv1 = fast_tanh(q1 * kk);
                ts += tv0 + tv1;
                short h0, l0, h1, l1;
                splitf(tv0, h0, l0); splitf(tv1, h1, l1);
                unsigned hh = (unsigned)(unsigned short)h0 | ((unsigned)(unsigned short)h1 << 16);
                unsigned ll = (unsigned)(unsigned short)l0 | ((unsigned)(unsigned short)l1 << 16);
                if (q == 0) { hp0 = hh; lp0 = ll; }
                else if (q == 1) { hp1 = hh; lp1 = ll; }
                else if (q == 2) { hp2 = hh; lp2 = ll; }
                else { hp3 = hh; lp3 = ll; }
                s_t2L[(2 * q) * 768 + d * 8 + j] = h0;
                s_t2L[(2 * q + 1) * 768 + d * 8 + j] = h1;
            }
            *(uint4*)&s_tH[j * 776 + d * 8] = make_uint4(hp0, hp1, hp2, hp3);
            *(uint4*)&s_tL[j * 776 + d * 8] = make_uint4(lp0, lp1, lp2, lp3);
            s_tsum[j * 96 + d] = ts;
        }
        __syncthreads();                                   // B4
        // P9: dump t2 (coalesced uint4, nt) + G-GEMM (asm MFMA, 3 accs, no LL)
        {
            uint32x4 tv = *(const uint32x4*)&s_t2L[tid * 8];
            __builtin_nontemporal_store(tv,
                (uint32x4*)&t2g[((size_t)(t * B_ + b)) * 6144 + tid * 8]);
        }
        {
            const int rt = wv % 6, kh = wv / 6;
            f32x4 aHH = {0,0,0,0}, aLH = {0,0,0,0}, aHL = {0,0,0,0};
#pragma unroll 4
            for (int s2 = 0; s2 < 12; ++s2) {
                int kb = kh * 12 + s2;
                bf16x8 ah = {}; bf16x8 al = {};
                if (col < 8) {
                    ah = *(const bf16x8*)&s_tH[col * 776 + kb * 32 + grp * 8];
                    al = *(const bf16x8*)&s_tL[col * 776 + kb * 32 + grp * 8];
                }
                int fo = ((rt * 24 + kb) * 64 + lane) * 8;
                bf16x8 bh = *(const bf16x8*)&W2H[fo];
                bf16x8 bl = *(const bf16x8*)&W2L[fo];
                aHH = mfma16v(ah, bh, aHH);
                aLH = mfma16v(al, bh, aLH);
                aHL = mfma16v(ah, bl, aHL);
            }
            MFMA_FENCE3(aHH, aLH, aHL);
            f32x4 accG;
#pragma unroll
            for (int reg = 0; reg < 4; ++reg) accG[reg] = (aHH[reg] + aLH[reg]) + aHL[reg];
            float* dst = (kh == 0) ? s_G0 : s_G1;
            if (grp < 2) {
#pragma unroll
                for (int reg = 0; reg < 4; ++reg)
                    dst[(grp * 4 + reg) * 96 + rt * 16 + col] = accG[reg];
            }
        }
        __syncthreads();                                   // B5
        // P10a: GWq partials
        { int oo = tid % 192, q = tid / 192; int jg = oo / C3, cc = oo % C3;
          float a = 0.f;
          for (int f = q * 24; f < q * 24 + 24; ++f)
              a += (s_G0[jg * 96 + f] + s_G1[jg * 96 + f]) * s_Wq[f * C3 + cc];
          s_scrB[tid] = a; }
        // P10b: S update (pass A — 12 accs only)
        {
            float sn[12];
#pragma unroll
            for (int ii = 0; ii < 12; ++ii) sn[ii] = 0.f;
#pragma unroll
            for (int j = 0; j < 8; ++j) {
                const float tj = s_tsum[j * 96 + de];
                const float4* vp = (const float4*)&s_v[j * 96 + ef0];
#pragma unroll
                for (int q4 = 0; q4 < 3; ++q4) {
                    float4 vv = vp[q4];
                    sn[q4*4+0] += tj*vv.x; sn[q4*4+1] += tj*vv.y;
                    sn[q4*4+2] += tj*vv.z; sn[q4*4+3] += tj*vv.w;
                }
            }
#pragma unroll
            for (int ii = 0; ii < 12; ++ii)
                s_rS[t13 + ii] = a1 * s_rS[t13 + ii] + sn[ii];
        }
        // P10c: Mi update (pass B — 12 accs only)
        {
            float r2[12];
#pragma unroll
            for (int ii = 0; ii < 12; ++ii) r2[ii] = 0.f;
#pragma unroll
            for (int j = 0; j < 8; ++j) {
                const float vj = s_v[j * 96 + de];
                const float4* g0 = (const float4*)&s_G0[j * 96 + ef0];
                const float4* g1 = (const float4*)&s_G1[j * 96 + ef0];
#pragma unroll
                for (int q4 = 0; q4 < 3; ++q4) {
                    float4 ga = g0[q4], gb = g1[q4];
                    r2[q4*4+0] += vj*(ga.x+gb.x); r2[q4*4+1] += vj*(ga.y+gb.y);
                    r2[q4*4+2] += vj*(ga.z+gb.z); r2[q4*4+3] += vj*(ga.w+gb.w);
                }
            }
#pragma unroll
            for (int ii = 0; ii < 12; ++ii)
                rMi[ii] += a3 * (r2[ii] + s_b2v[ef0 + ii]);
        }
        // no B6: next-iteration B1 orders s_scrB/s_v for the relocated P12'
    }
}

// ================= tail: grid 258, software-pipelined d-loop (builtin MFMA) =================
__global__ __launch_bounds__(384, 2) void stm_tail(
    const short* __restrict__ WrBH, const short* __restrict__ WrBL,
    const short* __restrict__ W3H, const short* __restrict__ W3L,
    const short* __restrict__ t2g, const short* __restrict__ vgb,
    const float* __restrict__ y0, const float* __restrict__ br,
    const float* __restrict__ W3f, const float* __restrict__ b3,
    float* __restrict__ zg, float* __restrict__ c0v, float* __restrict__ cbrv)
{
    __shared__ __attribute__((aligned(16))) short sPT[6 * 5120];   // 61440 B
    short* DyH = sPT;                 // overlay after PT consumed: 8t x 776 = 12416 B
    short* DyL = sPT + 6208;          // 12416 B

    const int tid = threadIdx.x;

    if (blockIdx.x >= 256) {          // c0 / cbr blocks (one-time GEMVs)
        float* red = (float*)sPT;
        const int o = tid & 63, seg = tid >> 6;     // seg 0..5, 128 i each
        if (blockIdx.x == 256) {
            float pa = 0.f;
            for (int i = seg * 128; i < seg * 128 + 128; ++i)
                pa += y0[i] * W3f[(size_t)i * 64 + o];
            red[seg * 64 + o] = pa;
            __syncthreads();
            if (tid < 64) {
                float s = 0.f;
                for (int q = 0; q < 6; ++q) s += red[q * 64 + tid];
                c0v[tid] = s;
            }
        } else {
            float pb = 0.f;
            for (int i = seg * 128; i < seg * 128 + 128; ++i)
                pb += br[i % 96] * W3f[(size_t)i * 64 + o];
            red[seg * 64 + o] = pb;
            __syncthreads();
            if (tid < 64) {
                float s = b3[tid];
                for (int q = 0; q < 6; ++q) s += red[q * 64 + tid];
                cbrv[tid] = s;
            }
        }
        return;
    }

    const int b = blockIdx.x & 127, tg = blockIdx.x >> 7;
    const int wv6 = tid >> 6, lane = tid & 63, col = lane & 15, grp = lane >> 4;
    const int rt6 = wv6;
    const int th = tg * 8;
    short* PTw = sPT + wv6 * 5120;

    bf16x8 Av[4][3];
#pragma unroll
    for (int p = 0; p < 4; ++p)
#pragma unroll
        for (int kf = 0; kf < 3; ++kf) {
            int t = th + 2 * p + (col >> 3);
            int j = col & 7;
            uint4 z = *(const uint4*)&vgb[((size_t)(t * B_ + b)) * 768 + j * 96 + kf * 32 + grp * 8];
            FragU F; F.u[0] = z.x; F.u[1] = z.y; F.u[2] = z.z; F.u[3] = z.w;
            Av[p][kf] = F.f;
        }
    f32x4 accD[8];
#pragma unroll
    for (int btl = 0; btl < 8; ++btl) accD[btl] = (f32x4){0.f, 0.f, 0.f, 0.f};

    FragU A2r[8];
    bf16x8 bhA[3], blA[3], bhB[3], blB[3];
#pragma unroll
    for (int kf = 0; kf < 3; ++kf) {
        const int fo = ((0 * 18 + rt6 * 3 + kf) * 64 + lane) * 8;
        bhA[kf] = *(const bf16x8*)&WrBH[fo];
        blA[kf] = *(const bf16x8*)&WrBL[fo];
    }

#define TAIL_BODY(DL, CH, CL, NH, NL)                                          \
    {                                                                          \
        const int d = g4 * 4 + (DL);                                           \
        if ((DL) < 3 || g4 < 23) {                                             \
            const int dn = d + 1;                                              \
            _Pragma("unroll")                                                  \
            for (int kf = 0; kf < 3; ++kf) {                                   \
                const int fo = ((dn * 18 + rt6 * 3 + kf) * 64 + lane) * 8;     \
                NH[kf] = *(const bf16x8*)&WrBH[fo];                            \
                NL[kf] = *(const bf16x8*)&WrBL[fo];                            \
            }                                                                  \
        }                                                                      \
        if ((DL) == 1) {                                                       \
            _Pragma("unroll")                                                  \
            for (int btl = 0; btl < 8; ++btl) {                                \
                A2r[btl].u[0] = 0; A2r[btl].u[1] = 0;                          \
                A2r[btl].u[2] = 0; A2r[btl].u[3] = 0;                          \
                if (col < 8) {                                                 \
                    const int tt = th + btl;                                   \
                    uint4 z = *(const uint4*)&t2g[((size_t)(tt * B_ + b)) * 6144 \
                              + col * 768 + g4 * 32 + grp * 8];                \
                    A2r[btl].u[0] = z.x; A2r[btl].u[1] = z.y;                  \
                    A2r[btl].u[2] = z.z; A2r[btl].u[3] = z.w;                  \
                }                                                              \
            }                                                                  \
        }                                                                      \
        f32x4 aPv[4];                                                          \
        _Pragma("unroll")                                                      \
        for (int p = 0; p < 4; ++p) aPv[p] = (f32x4){0.f, 0.f, 0.f, 0.f};      \
        _Pragma("unroll")                                                      \
        for (int kf = 0; kf < 3; ++kf) {                                       \
            _Pragma("unroll")                                                  \
            for (int p = 0; p < 4; ++p) aPv[p] = mfma16(Av[p][kf], CH[kf], aPv[p]); \
            _Pragma("unroll")                                                  \
            for (int p = 0; p < 4; ++p) aPv[p] = mfma16(Av[p][kf], CL[kf], aPv[p]); \
        }                                                                      \
        {                                                                      \
            const int j0 = (grp & 1) * 4;                                      \
            const int bo = grp >> 1;                                           \
            _Pragma("unroll")                                                  \
            for (int p = 0; p < 4; ++p) {                                      \
                const int btl = 2 * p + bo;                                    \
                uint2 uu;                                                      \
                uu.x = (unsigned)(unsigned short)f2bf(aPv[p][0]) |             \
                       ((unsigned)(unsigned short)f2bf(aPv[p][1]) << 16);      \
                uu.y = (unsigned)(unsigned short)f2bf(aPv[p][2]) |             \
                       ((unsigned)(unsigned short)f2bf(aPv[p][3]) << 16);      \
                *(uint2*)&PTw[btl * 640 + col * 40 + (DL) * 8 + j0] = uu;      \
            }                                                                  \
        }                                                                      \
        if ((DL) == 3) {                                                       \
            _Pragma("unroll")                                                  \
            for (int btl = 0; btl < 8; ++btl) {                                \
                bf16x8 B2 = *(const bf16x8*)&PTw[btl * 640 + col * 40 + grp * 8]; \
                accD[btl] = mfma16(A2r[btl].f, B2, accD[btl]);                 \
            }                                                                  \
        }                                                                      \
    }

    for (int g4 = 0; g4 < 24; ++g4) {
        TAIL_BODY(0, bhA, blA, bhB, blB)
        TAIL_BODY(1, bhB, blB, bhA, blA)
        TAIL_BODY(2, bhA, blA, bhB, blB)
        TAIL_BODY(3, bhB, blB, bhA, blA)
    }
#undef TAIL_BODY

    __syncthreads();
    // Dy split planes for this block's 8 t (local rows 0..7)
    if (grp < 2) {
#pragma unroll
        for (int btl = 0; btl < 8; ++btl)
#pragma unroll
            for (int reg = 0; reg < 4; ++reg) {
                short h, l; splitf(accD[btl][reg], h, l);
                int idx = btl * 776 + (grp * 4 + reg) * 96 + rt6 * 16 + col;
                DyH[idx] = h; DyL[idx] = l;
            }
    }
    __syncthreads();
    // Z-GEMM: waves 0..3 = o-tiles, A rows = local t (8 valid), k = 768
    if (wv6 < 4) {
        const int ot = wv6;
        f32x4 zHH = {0,0,0,0}, zLH = {0,0,0,0}, zHL = {0,0,0,0};
#pragma unroll 4
        for (int kb = 0; kb < 24; ++kb) {
            bf16x8 ah = {}; bf16x8 al = {};
            if (col < 8) {
                ah = *(const bf16x8*)&DyH[col * 776 + kb * 32 + grp * 8];
                al = *(const bf16x8*)&DyL[col * 776 + kb * 32 + grp * 8];
            }
            int fo = ((ot * 24 + kb) * 64 + lane) * 8;
            bf16x8 bhw = *(const bf16x8*)&W3H[fo];
            bf16x8 blw = *(const bf16x8*)&W3L[fo];
            zHH = mfma16(ah, bhw, zHH);
            zLH = mfma16(al, bhw, zLH);
            zHL = mfma16(ah, blw, zHL);
        }
        if (grp < 2) {
#pragma unroll
            for (int reg = 0; reg < 4; ++reg) {
                int tl = grp * 4 + reg;
                zg[((size_t)(b * 16 + th + tl)) * 64 + ot * 16 + col] = zHH[reg] + zLH[reg] + zHL[reg];
            }
        }
    }
}

// ================= fin: pure scan over t, grid 128 x 64 =================
__global__ __launch_bounds__(64) void stm_fin(
    const float* __restrict__ a1p, const float* __restrict__ zg,
    const float* __restrict__ c0v, const float* __restrict__ cbrv,
    float* __restrict__ out)
{
    const int tid = threadIdx.x, b = blockIdx.x;
    const float a1 = a1p[0];
    float u = c0v[tid];
    const float cbr = cbrv[tid];
    for (int t = 0; t < T_; ++t) {
        u = a1 * u + zg[((size_t)(b * 16 + t)) * 64 + tid];
        out[((size_t)(t * B_ + b)) * OUT_ + tid] = u + cbr;
    }
}

extern "C" void kernel_launch(void* const* d_in, const int* in_sizes, int n_in,
                              void* d_out, int out_size, void* d_ws, size_t ws_size,
                              hipStream_t stream) {
    const float* x         = (const float*)d_in[0];
    const float* Wqkv      = (const float*)d_in[1];
    const float* bqkv      = (const float*)d_in[2];
    const float* ln_g      = (const float*)d_in[3];
    const float* ln_b      = (const float*)d_in[4];
    const float* a1        = (const float*)d_in[5];
    const float* a2        = (const float*)d_in[6];
    const float* a3        = (const float*)d_in[7];
    const float* W2        = (const float*)d_in[8];
    const float* b2        = (const float*)d_in[9];
    const float* Wr        = (const float*)d_in[10];
    const float* br        = (const float*)d_in[11];
    const float* W3        = (const float*)d_in[12];
    const float* b3        = (const float*)d_in[13];
    const float* item_bias = (const float*)d_in[14];
    const float* rel_bias  = (const float*)d_in[15];
    float* out = (float*)d_out;

    char* ws = (char*)d_ws;
    short* WrBH = (short*)ws;                          // 1,769,472 B
    short* WrBL = (short*)(ws + 1769472);              // 1,769,472 B
    short* W2H  = (short*)(ws + 3538944);              //   147,456 B
    short* W2L  = (short*)(ws + 3686400);              //   147,456 B
    short* W3H  = (short*)(ws + 3833856);              //    98,304 B
    short* W3L  = (short*)(ws + 3932160);              //    98,304 B
    float* y0   = (float*)(ws + 4030464);              //     3,072 B
    short* t2g  = (short*)(ws + 4034048);              // 25,165,824 B
    short* vgb  = (short*)(ws + 29199872);             //  3,145,728 B
    float* zg   = (float*)(ws + 32345600);             //    524,288 B
    float* c0v  = (float*)(ws + 32869888);             //       256 B
    float* cbrv = (float*)(ws + 32870144);             //       256 B

    hipMemsetAsync(y0, 0, 3072, stream);
    hipLaunchKernelGGL(prep_mega, dim3(208), dim3(768), 0, stream,
                       Wr, W2, W3, rel_bias, WrBH, WrBL, W2H, W2L, W3H, W3L, y0);
    hipLaunchKernelGGL(stm_rec, dim3(B_), dim3(768), 0, stream,
                       x, Wqkv, bqkv, ln_g, ln_b, a1, a2, a3,
                       b2, item_bias, rel_bias, W2H, W2L, t2g, vgb);
    hipLaunchKernelGGL(stm_tail, dim3(258), dim3(384), 0, stream,
                       WrBH, WrBL, W3H, W3L, t2g, vgb,
                       y0, br, W3, b3, zg, c0v, cbrv);
    hipLaunchKernelGGL(stm_fin, dim3(B_), dim3(64), 0, stream,
                       a1, zg, c0v, cbrv, out);
}